// Round 1
// 398.456 us; speedup vs baseline: 1.0870x; 1.0870x over previous
//
#include <hip/hip_runtime.h>
#include <cstdint>
#include <cstddef>

// Problem constants (fixed by the reference)
#define NN 16384      // nodes
#define DIN 1024      // hid_size
#define DMID 1500     // hidden_size (logical)
#define DMIDP 1536    // padded to multiple of 256
#define NE 131072     // edges

typedef __bf16 bf16;
typedef __bf16 bf16x4 __attribute__((ext_vector_type(4)));
typedef __bf16 bf16x8 __attribute__((ext_vector_type(8)));
typedef float f32x4 __attribute__((ext_vector_type(4)));

#define GLOBAL_AS __attribute__((address_space(1)))
#define LDS_AS __attribute__((address_space(3)))

__device__ __forceinline__ void gload_lds16(const bf16* g, bf16* l) {
    // async 16B/lane global->LDS; LDS dest is wave-uniform base + lane*16
    __builtin_amdgcn_global_load_lds((GLOBAL_AS const unsigned int*)(g),
                                     (LDS_AS unsigned int*)(l), 16, 0, 0);
}

// raw barrier (no vmcnt drain) + counted waits — T3/T4 essentials
#define SBAR() asm volatile("s_barrier" ::: "memory")
#define WAITV_(N) asm volatile("s_waitcnt vmcnt(" #N ")" ::: "memory")
#define WAITV(N) WAITV_(N)
#define WAITL0()                                             \
    do {                                                     \
        asm volatile("s_waitcnt lgkmcnt(0)" ::: "memory");   \
        __builtin_amdgcn_sched_barrier(0);                   \
    } while (0)

// ---------------- CSR build + normalization ----------------
__global__ void k_zero_cnt(int* cnt) {
    cnt[blockIdx.x * 256 + threadIdx.x] = 0;
}

__global__ void k_count(const int* __restrict__ dst, int* cnt) {
    int e = blockIdx.x * 256 + threadIdx.x;
    atomicAdd(&cnt[dst[e]], 1);
}

// single block, 1024 threads, 16 nodes each.
// rowptr = exclusive scan of PADDED counts (pad to multiple of 8); cursor = start; isd.
__global__ __launch_bounds__(1024) void k_scan(const int* __restrict__ cnt,
                                               int* __restrict__ rowptr,
                                               int* __restrict__ cursor,
                                               float* __restrict__ isd) {
    __shared__ int sums[1024];
    int t = threadIdx.x;
    int base = t * 16;
    int v[16], p[16];
    int s = 0;
#pragma unroll
    for (int k = 0; k < 16; ++k) {
        v[k] = cnt[base + k];
        p[k] = (v[k] + 7) & ~7;  // padded row length (multiple of 8)
        s += p[k];
    }
    sums[t] = s;
    __syncthreads();
    for (int off = 1; off < 1024; off <<= 1) {
        int y = (t >= off) ? sums[t - off] : 0;
        __syncthreads();
        sums[t] += y;
        __syncthreads();
    }
    int run = sums[t] - s;  // exclusive prefix
#pragma unroll
    for (int k = 0; k < 16; ++k) {
        rowptr[base + k] = run;
        cursor[base + k] = run;
        isd[base + k] = rsqrtf((float)(v[k] + 1));  // +1 self-loop
        run += p[k];
    }
    if (t == 1023) rowptr[NN] = run;
}

__global__ void k_fill(const int* __restrict__ src, const int* __restrict__ dst,
                       int* cursor, const float* __restrict__ isd,
                       int* __restrict__ csr_src, float* __restrict__ csr_w) {
    int e = blockIdx.x * 256 + threadIdx.x;
    int s = src[e], d = dst[e];
    int pos = atomicAdd(&cursor[d], 1);
    csr_src[pos] = s;
    csr_w[pos] = isd[s] * isd[d];
}

// fill pad slots: src = self (L1-hot row), w = 0 (contributes nothing)
__global__ void k_pad(const int* __restrict__ cnt, const int* __restrict__ rowptr,
                      int* __restrict__ csr_src, float* __restrict__ csr_w) {
    int i = blockIdx.x * 256 + threadIdx.x;
    int c = cnt[i];
    int p = (c + 7) & ~7;
    int base = rowptr[i];
    for (int q = c; q < p; ++q) {
        csr_src[base + q] = i;
        csr_w[base + q] = 0.0f;
    }
}

// ---------------- conversions ----------------
__global__ void k_cvt_x(const float4* __restrict__ x, bf16x4* __restrict__ xb) {
    int i = blockIdx.x * 256 + threadIdx.x;  // NN*DIN/4 total
    float4 v = x[i];
    bf16x4 o;
    o[0] = (bf16)v.x; o[1] = (bf16)v.y; o[2] = (bf16)v.z; o[3] = (bf16)v.w;
    xb[i] = o;
}

// W1 [1024][1500] f32 row-major -> W1b [1536][1024] bf16 (transposed, n-pad zero)
__global__ void k_cvt_w1(const float* __restrict__ W1, bf16* __restrict__ W1b) {
    int n = blockIdx.x;  // 0..1535
    for (int k = threadIdx.x; k < DIN; k += 256)
        W1b[n * DIN + k] = (n < DMID) ? (bf16)W1[(size_t)k * DMID + n] : (bf16)0.0f;
}

// W2 [1500][1024] f32 row-major -> W2b [1024][1536] bf16 (transposed, k-pad zero)
__global__ void k_cvt_w2(const float* __restrict__ W2, bf16* __restrict__ W2b) {
    int n = blockIdx.x;  // 0..1023
    for (int k = threadIdx.x; k < DMIDP; k += 256)
        W2b[n * DMIDP + k] = (k < DMID) ? (bf16)W2[(size_t)k * DIN + n] : (bf16)0.0f;
}

// ---------------- GEMM: C[M,N] = A[M,K] @ Bt[N,K]^T, bf16 in / bf16 out ----------------
// 256x256 tile, BK=64, 8 waves (2M x 4N), per-wave 128x64 output.
// T2: XOR bank-swizzle (slot ^= row&7 per 16B slot), applied on the GLOBAL source
//     (global_load_lds writes linearly) and on the ds_read address — same involution.
// T3/T4: double-buffered K-tiles, prefetch issued at tile boundary into the dead
//     buffer, single counted s_waitcnt vmcnt(8) per K-tile (never 0 in steady state),
//     raw s_barrier (no drain).
// T5: s_setprio(1) around each 16-MFMA phase cluster.
// 4 phases per K-tile: (ks,mh) in {(0,0),(0,1),(1,0),(1,1)}; B-frags reused across mh.
template <int K, int N, bool RELU_BIAS>
__global__ __launch_bounds__(512, 2) void gemm256(const bf16* __restrict__ A,
                                                  const bf16* __restrict__ Bt,
                                                  bf16* __restrict__ C,
                                                  const float* __restrict__ bias) {
    constexpr int NT = K / 64;
    __shared__ __align__(16) bf16 lds[2][2][256 * 64];  // [buf][A/B][row*64+col] = 128 KB
    const int tid = threadIdx.x;
    const int w = tid >> 6;
    const int lane = tid & 63;
    const int bm = blockIdx.x, bn = blockIdx.y;
    const int fr = lane & 15, fq = lane >> 4;
    const int wm = w >> 2;   // 0..1 : M half (128 rows)
    const int wn = w & 3;    // 0..3 : N quarter (64 cols)
    const int sx = fr & 7;   // read-side swizzle mask

    // staging: wave w, round r covers tile rows r*64 + w*8 .. +7 (1 KB per gload).
    // lane l -> row_local = l>>3, stored slot = l&7 holds logical slot (l&7)^(l>>3)
    // (row&7 == l>>3 here), so fetch global slot pre-swizzled.
    const int lrow = lane >> 3;
    const int lslot = (lane & 7) ^ lrow;
    const bf16* gA = A + (size_t)(bm * 256 + w * 8 + lrow) * K + lslot * 8;
    const bf16* gB = Bt + (size_t)(bn * 256 + w * 8 + lrow) * K + lslot * 8;
    bf16* lA0 = &lds[0][0][0] + w * 512;
    bf16* lB0 = &lds[0][1][0] + w * 512;
    bf16* lA1 = &lds[1][0][0] + w * 512;
    bf16* lB1 = &lds[1][1][0] + w * 512;

    f32x4 acc[8][4];
#pragma unroll
    for (int i = 0; i < 8; ++i)
#pragma unroll
        for (int j = 0; j < 4; ++j) acc[i][j] = {0.f, 0.f, 0.f, 0.f};

// stage K-tile t (8 global_load_lds per wave = the vmcnt unit of account)
#define STAGE(T, LA, LB)                                                  \
    do {                                                                  \
        const bf16* _ga = gA + (size_t)(T) * 64;                          \
        const bf16* _gb = gB + (size_t)(T) * 64;                          \
        _Pragma("unroll") for (int r = 0; r < 4; ++r)                     \
            gload_lds16(_ga + (size_t)r * (64 * K), (LA) + r * 4096);     \
        _Pragma("unroll") for (int r = 0; r < 4; ++r)                     \
            gload_lds16(_gb + (size_t)r * (64 * K), (LB) + r * 4096);     \
    } while (0)

// ds_read a 4-frag A subtile / 4-frag B subtile (swizzled addresses)
#define LDA4(BUF, MH, KS)                                                             \
    _Pragma("unroll") for (int mt = 0; mt < 4; ++mt) {                                \
        int row = wm * 128 + (MH) * 64 + mt * 16 + fr;                                \
        int sl = (((KS) << 2) | fq) ^ sx;                                             \
        af[mt] = *(const bf16x8*)((const char*)&lds[BUF][0][0] + row * 128 + sl * 16);\
    }
#define LDB4(BUF, KS)                                                                 \
    _Pragma("unroll") for (int nt = 0; nt < 4; ++nt) {                                \
        int row = wn * 64 + nt * 16 + fr;                                             \
        int sl = (((KS) << 2) | fq) ^ sx;                                             \
        bq[nt] = *(const bf16x8*)((const char*)&lds[BUF][1][0] + row * 128 + sl * 16);\
    }
#define MFMA16(MH)                                                                    \
    _Pragma("unroll") for (int mt = 0; mt < 4; ++mt)                                  \
    _Pragma("unroll") for (int nt = 0; nt < 4; ++nt)                                  \
        acc[(MH) * 4 + mt][nt] = __builtin_amdgcn_mfma_f32_16x16x32_bf16(             \
            af[mt], bq[nt], acc[(MH) * 4 + mt][nt], 0, 0, 0);

    // prologue: tiles 0 and 1 in flight; wait only tile 0 (8 newest stay in flight)
    STAGE(0, lA0, lB0);
    STAGE(1, lA1, lB1);
    WAITV(8);
    SBAR();

#pragma unroll 2
    for (int t = 0; t < NT; ++t) {
        const int b = t & 1;
        bf16x8 af[4], bq[4];
        // phase 1: (ks=0, mh=0) + B(ks=0)
        LDB4(b, 0); LDA4(b, 0, 0);
        SBAR(); WAITL0();
        __builtin_amdgcn_s_setprio(1); MFMA16(0); __builtin_amdgcn_s_setprio(0);
        SBAR();
        // phase 2: (ks=0, mh=1), reuse B(ks=0)
        LDA4(b, 1, 0);
        SBAR(); WAITL0();
        __builtin_amdgcn_s_setprio(1); MFMA16(1); __builtin_amdgcn_s_setprio(0);
        SBAR();
        // phase 3: (ks=1, mh=0) + B(ks=1)
        LDB4(b, 1); LDA4(b, 0, 1);
        SBAR(); WAITL0();
        __builtin_amdgcn_s_setprio(1); MFMA16(0); __builtin_amdgcn_s_setprio(0);
        SBAR();
        // phase 4: (ks=1, mh=1)
        LDA4(b, 1, 1);
        SBAR(); WAITL0();
        __builtin_amdgcn_s_setprio(1); MFMA16(1); __builtin_amdgcn_s_setprio(0);
        SBAR();
        // boundary: buffer b is dead (all waves past their reads via the barrier
        // above). Prefetch tile t+2 into it; counted wait ensures tile t+1 landed
        // while t+2's 8 loads stay in flight across the barrier.
        if (t + 2 < NT) {
            if (b == 0) { STAGE(t + 2, lA0, lB0); } else { STAGE(t + 2, lA1, lB1); }
            WAITV(8);
            SBAR();
        } else if (t + 1 < NT) {
            WAITV(0);
            SBAR();
        }
    }
#undef STAGE
#undef LDA4
#undef LDB4
#undef MFMA16

    // epilogue: C/D layout (verified m89/m91): col = lane&15, row = (lane>>4)*4 + reg
    float bv[4];
    if (RELU_BIAS) {
#pragma unroll
        for (int nt = 0; nt < 4; ++nt) {
            int col = bn * 256 + wn * 64 + nt * 16 + fr;
            bv[nt] = (col < DMID) ? bias[col] : 0.0f;
        }
    }
#pragma unroll
    for (int mq = 0; mq < 8; ++mq) {
        int row0 = bm * 256 + wm * 128 + mq * 16 + fq * 4;
#pragma unroll
        for (int nt = 0; nt < 4; ++nt) {
            int col = bn * 256 + wn * 64 + nt * 16 + fr;
#pragma unroll
            for (int r = 0; r < 4; ++r) {
                float v = acc[mq][nt][r];
                if (RELU_BIAS) v = fmaxf(v + bv[nt], 0.0f);
                C[(size_t)(row0 + r) * N + col] = (bf16)v;
            }
        }
    }
}

// ---------------- aggregation (CSR gather, barrier-free) ----------------
// XA[i] = isd_i^2 * X[i] + sum_j w_ij * X[j], 1024-wide bf16 in/out
__global__ __launch_bounds__(128) void k_aggX(const bf16* __restrict__ X,
                                              const int* __restrict__ rowptr,
                                              const int* __restrict__ csr_src,
                                              const float* __restrict__ csr_w,
                                              const float* __restrict__ isd,
                                              bf16* __restrict__ XA) {
    int i = blockIdx.x;
    int t = threadIdx.x;      // 128 threads * 8 cols = 1024
    int c0 = t * 8;
    int beg = rowptr[i], end = rowptr[i + 1];  // uniform; (end-beg) % 8 == 0
    float wi = isd[i];
    float w0 = wi * wi;
    float a[8];
    bf16x8 h = *(const bf16x8*)&X[(size_t)i * DIN + c0];
#pragma unroll
    for (int k = 0; k < 8; ++k) a[k] = w0 * (float)h[k];
    for (int e = beg; e < end; e += 8) {
        int j[8];
        float w[8];
        bf16x8 hv[8];
#pragma unroll
        for (int q = 0; q < 8; ++q) { j[q] = csr_src[e + q]; w[q] = csr_w[e + q]; }
#pragma unroll
        for (int q = 0; q < 8; ++q)
            hv[q] = *(const bf16x8*)&X[(size_t)j[q] * DIN + c0];
#pragma unroll
        for (int q = 0; q < 8; ++q)
#pragma unroll
            for (int k = 0; k < 8; ++k) a[k] += w[q] * (float)hv[q][k];
    }
    bf16x8 o;
#pragma unroll
    for (int k = 0; k < 8; ++k) o[k] = (bf16)a[k];
    *(bf16x8*)&XA[(size_t)i * DIN + c0] = o;
}

// layer 2: out[i] = isd_i^2 * H[i] + sum_j w_ij * H[j] + b2, f32 out
__global__ __launch_bounds__(128) void k_agg2(const bf16* __restrict__ H,
                                              const int* __restrict__ rowptr,
                                              const int* __restrict__ csr_src,
                                              const float* __restrict__ csr_w,
                                              const float* __restrict__ isd,
                                              const float* __restrict__ b2,
                                              float* __restrict__ out) {
    int i = blockIdx.x;
    int t = threadIdx.x;      // 128 threads * 8 cols = 1024
    int c0 = t * 8;
    int beg = rowptr[i], end = rowptr[i + 1];
    float wi = isd[i];
    float w0 = wi * wi;
    float a[8];
    bf16x8 h = *(const bf16x8*)&H[(size_t)i * DIN + c0];
#pragma unroll
    for (int k = 0; k < 8; ++k) a[k] = w0 * (float)h[k];
    for (int e = beg; e < end; e += 8) {
        int j[8];
        float w[8];
        bf16x8 hv[8];
#pragma unroll
        for (int q = 0; q < 8; ++q) { j[q] = csr_src[e + q]; w[q] = csr_w[e + q]; }
#pragma unroll
        for (int q = 0; q < 8; ++q)
            hv[q] = *(const bf16x8*)&H[(size_t)j[q] * DIN + c0];
#pragma unroll
        for (int q = 0; q < 8; ++q)
#pragma unroll
            for (int k = 0; k < 8; ++k) a[k] += w[q] * (float)hv[q][k];
    }
    float4 o0, o1;
    o0.x = a[0] + b2[c0 + 0]; o0.y = a[1] + b2[c0 + 1];
    o0.z = a[2] + b2[c0 + 2]; o0.w = a[3] + b2[c0 + 3];
    o1.x = a[4] + b2[c0 + 4]; o1.y = a[5] + b2[c0 + 5];
    o1.z = a[6] + b2[c0 + 6]; o1.w = a[7] + b2[c0 + 7];
    *(float4*)&out[(size_t)i * DIN + c0] = o0;
    *(float4*)&out[(size_t)i * DIN + c0 + 4] = o1;
}

extern "C" void kernel_launch(void* const* d_in, const int* in_sizes, int n_in,
                              void* d_out, int out_size, void* d_ws, size_t ws_size,
                              hipStream_t stream) {
    const float* x = (const float*)d_in[0];
    const int* ei = (const int*)d_in[1];
    const float* W1 = (const float*)d_in[2];
    const float* b1 = (const float*)d_in[3];
    const float* W2 = (const float*)d_in[4];
    const float* b2 = (const float*)d_in[5];
    float* out = (float*)d_out;
    const int* src = ei;
    const int* dst = ei + NE;

    // workspace layout (bytes), total ~122 MB
    char* ws = (char*)d_ws;
    int* cnt      = (int*)(ws + 0);          //  64 KB
    int* cursor   = (int*)(ws + 65536);      //  64 KB
    float* isd    = (float*)(ws + 131072);   //  64 KB
    int* rowptr   = (int*)(ws + 196608);     // 128 KB (NN+1 ints)
    int* csr_src  = (int*)(ws + 327680);     //   2 MB (padded <= 245760 entries)
    float* csr_w  = (float*)(ws + 2424832);  //   2 MB
    bf16* Xb      = (bf16*)(ws + 4521984);   // 33.55 MB (16384x1024)
    bf16* XA      = (bf16*)(ws + 38076416);  // 33.55 MB — reused as H2b
    bf16* W1b     = (bf16*)(ws + 71630848);  //  3.15 MB (1536x1024, transposed)
    bf16* W2b     = (bf16*)(ws + 74776576);  //  3.15 MB (1024x1536, transposed)
    bf16* Y1b     = (bf16*)(ws + 77922304);  // 50.33 MB (16384x1536)
    bf16* H2b     = XA;                      // XA dead after GEMM1

    // CSR + normalization
    k_zero_cnt<<<NN / 256, 256, 0, stream>>>(cnt);
    k_count<<<NE / 256, 256, 0, stream>>>(dst, cnt);
    k_scan<<<1, 1024, 0, stream>>>(cnt, rowptr, cursor, isd);
    k_fill<<<NE / 256, 256, 0, stream>>>(src, dst, cursor, isd, csr_src, csr_w);
    k_pad<<<NN / 256, 256, 0, stream>>>(cnt, rowptr, csr_src, csr_w);

    // bf16 conversions
    k_cvt_x<<<NN * DIN / 4 / 256, 256, 0, stream>>>((const float4*)x, (bf16x4*)Xb);
    k_cvt_w1<<<DMIDP, 256, 0, stream>>>(W1, W1b);
    k_cvt_w2<<<DIN, 256, 0, stream>>>(W2, W2b);

    // layer 1: XA = A_hat @ X ; Y1 = relu(XA @ W1 + b1)   [agg commutes with linear]
    k_aggX<<<NN, 128, 0, stream>>>(Xb, rowptr, csr_src, csr_w, isd, XA);
    dim3 g1(NN / 256, DMIDP / 256);
    gemm256<DIN, DMIDP, true><<<g1, 512, 0, stream>>>(XA, W1b, Y1b, b1);

    // layer 2: H2 = Y1 @ W2 ; out = A_hat @ H2 + b2
    dim3 g2(NN / 256, DIN / 256);
    gemm256<DMIDP, DIN, false><<<g2, 512, 0, stream>>>(Y1b, W2b, H2b, nullptr);
    k_agg2<<<NN, 128, 0, stream>>>(H2b, rowptr, csr_src, csr_w, isd, b2, out);
}

// Round 2
// 398.159 us; speedup vs baseline: 1.0878x; 1.0007x over previous
//
#include <hip/hip_runtime.h>
#include <cstdint>
#include <cstddef>

// Problem constants (fixed by the reference)
#define NN 16384      // nodes
#define DIN 1024      // hid_size
#define DMID 1500     // hidden_size (logical)
#define DMIDP 1536    // padded to multiple of 256
#define NE 131072     // edges

typedef __bf16 bf16;
typedef __bf16 bf16x4 __attribute__((ext_vector_type(4)));
typedef __bf16 bf16x8 __attribute__((ext_vector_type(8)));
typedef float f32x4 __attribute__((ext_vector_type(4)));

#define GLOBAL_AS __attribute__((address_space(1)))
#define LDS_AS __attribute__((address_space(3)))

__device__ __forceinline__ void gload_lds16(const bf16* g, bf16* l) {
    // async 16B/lane global->LDS; LDS dest is wave-uniform base + lane*16
    __builtin_amdgcn_global_load_lds((GLOBAL_AS const unsigned int*)(g),
                                     (LDS_AS unsigned int*)(l), 16, 0, 0);
}

// raw barrier (no vmcnt drain) + counted waits — T3/T4 essentials
#define SBAR() asm volatile("s_barrier" ::: "memory")
#define WAITV_(N) asm volatile("s_waitcnt vmcnt(" #N ")" ::: "memory")
#define WAITV(N) WAITV_(N)
// R1 post-mortem: the old WAITL0 = lgkm(0) + sched_barrier(0) was an m141-style
// order pin — it forced {all 24 reads}->{all MFMA} lockstep (MfmaUtil 26.5%,
// LDS pipe 33%). ds_reads here are PLAIN loads, so the compiler's scoreboard
// emits fine-grained lgkm waits per MFMA (rule 18 applies to asm ds_reads only).
// Keep the bare lgkm(0): it is the cross-wave WAR fence (drains this wave's
// reads before it passes the post-MFMA barrier, so boundary STAGE can't clobber
// in-flight reads). MFMAs may hoist across it — harmless and desired.
#define WAITL0() asm volatile("s_waitcnt lgkmcnt(0)" ::: "memory")

// ---------------- CSR build + normalization ----------------
__global__ void k_zero_cnt(int* cnt) {
    cnt[blockIdx.x * 256 + threadIdx.x] = 0;
}

__global__ void k_count(const int* __restrict__ dst, int* cnt) {
    int e = blockIdx.x * 256 + threadIdx.x;
    atomicAdd(&cnt[dst[e]], 1);
}

// single block, 1024 threads, 16 nodes each.
// rowptr = exclusive scan of PADDED counts (pad to multiple of 8); cursor = start; isd.
__global__ __launch_bounds__(1024) void k_scan(const int* __restrict__ cnt,
                                               int* __restrict__ rowptr,
                                               int* __restrict__ cursor,
                                               float* __restrict__ isd) {
    __shared__ int sums[1024];
    int t = threadIdx.x;
    int base = t * 16;
    int v[16], p[16];
    int s = 0;
#pragma unroll
    for (int k = 0; k < 16; ++k) {
        v[k] = cnt[base + k];
        p[k] = (v[k] + 7) & ~7;  // padded row length (multiple of 8)
        s += p[k];
    }
    sums[t] = s;
    __syncthreads();
    for (int off = 1; off < 1024; off <<= 1) {
        int y = (t >= off) ? sums[t - off] : 0;
        __syncthreads();
        sums[t] += y;
        __syncthreads();
    }
    int run = sums[t] - s;  // exclusive prefix
#pragma unroll
    for (int k = 0; k < 16; ++k) {
        rowptr[base + k] = run;
        cursor[base + k] = run;
        isd[base + k] = rsqrtf((float)(v[k] + 1));  // +1 self-loop
        run += p[k];
    }
    if (t == 1023) rowptr[NN] = run;
}

__global__ void k_fill(const int* __restrict__ src, const int* __restrict__ dst,
                       int* cursor, const float* __restrict__ isd,
                       int* __restrict__ csr_src, float* __restrict__ csr_w) {
    int e = blockIdx.x * 256 + threadIdx.x;
    int s = src[e], d = dst[e];
    int pos = atomicAdd(&cursor[d], 1);
    csr_src[pos] = s;
    csr_w[pos] = isd[s] * isd[d];
}

// fill pad slots: src = self (L1-hot row), w = 0 (contributes nothing)
__global__ void k_pad(const int* __restrict__ cnt, const int* __restrict__ rowptr,
                      int* __restrict__ csr_src, float* __restrict__ csr_w) {
    int i = blockIdx.x * 256 + threadIdx.x;
    int c = cnt[i];
    int p = (c + 7) & ~7;
    int base = rowptr[i];
    for (int q = c; q < p; ++q) {
        csr_src[base + q] = i;
        csr_w[base + q] = 0.0f;
    }
}

// ---------------- conversions ----------------
__global__ void k_cvt_x(const float4* __restrict__ x, bf16x4* __restrict__ xb) {
    int i = blockIdx.x * 256 + threadIdx.x;  // NN*DIN/4 total
    float4 v = x[i];
    bf16x4 o;
    o[0] = (bf16)v.x; o[1] = (bf16)v.y; o[2] = (bf16)v.z; o[3] = (bf16)v.w;
    xb[i] = o;
}

// W1 [1024][1500] f32 row-major -> W1b [1536][1024] bf16 (transposed, n-pad zero)
__global__ void k_cvt_w1(const float* __restrict__ W1, bf16* __restrict__ W1b) {
    int n = blockIdx.x;  // 0..1535
    for (int k = threadIdx.x; k < DIN; k += 256)
        W1b[n * DIN + k] = (n < DMID) ? (bf16)W1[(size_t)k * DMID + n] : (bf16)0.0f;
}

// W2 [1500][1024] f32 row-major -> W2b [1024][1536] bf16 (transposed, k-pad zero)
__global__ void k_cvt_w2(const float* __restrict__ W2, bf16* __restrict__ W2b) {
    int n = blockIdx.x;  // 0..1023
    for (int k = threadIdx.x; k < DMIDP; k += 256)
        W2b[n * DMIDP + k] = (k < DMID) ? (bf16)W2[(size_t)k * DIN + n] : (bf16)0.0f;
}

// ---------------- GEMM: C[M,N] = A[M,K] @ Bt[N,K]^T, bf16 in / bf16 out ----------------
// 256x256 tile, BK=64, 8 waves (2M x 4N), per-wave 128x64 output.
// T2: XOR bank-swizzle (slot ^= row&7 per 16B slot), source-side pre-swizzle +
//     swizzled ds_read (both-sides involution, rule #21). R1: conflicts = 0.
// T3/T4: double-buffered K-tiles, prefetch at tile boundary into the dead
//     buffer, counted s_waitcnt vmcnt(8) per K-tile (never 0 in steady state),
//     raw s_barrier (no drain).
// T5: s_setprio(1) around each 16-MFMA phase cluster.
// 4 phases per K-tile: (ks,mh) in {(0,0),(0,1),(1,0),(1,1)}; B-frags reused across mh.
// R2: no sched_barrier pins — compiler schedules reads/MFMA with fine lgkm waits.
template <int K, int N, bool RELU_BIAS>
__global__ __launch_bounds__(512, 2) void gemm256(const bf16* __restrict__ A,
                                                  const bf16* __restrict__ Bt,
                                                  bf16* __restrict__ C,
                                                  const float* __restrict__ bias) {
    constexpr int NT = K / 64;
    __shared__ __align__(16) bf16 lds[2][2][256 * 64];  // [buf][A/B][row*64+col] = 128 KB
    const int tid = threadIdx.x;
    const int w = tid >> 6;
    const int lane = tid & 63;
    const int bm = blockIdx.x, bn = blockIdx.y;
    const int fr = lane & 15, fq = lane >> 4;
    const int wm = w >> 2;   // 0..1 : M half (128 rows)
    const int wn = w & 3;    // 0..3 : N quarter (64 cols)
    const int sx = fr & 7;   // read-side swizzle mask

    // staging: wave w, round r covers tile rows r*64 + w*8 .. +7 (1 KB per gload).
    // lane l -> row_local = l>>3, stored slot = l&7 holds logical slot (l&7)^(l>>3)
    // (row&7 == l>>3 here), so fetch global slot pre-swizzled.
    const int lrow = lane >> 3;
    const int lslot = (lane & 7) ^ lrow;
    const bf16* gA = A + (size_t)(bm * 256 + w * 8 + lrow) * K + lslot * 8;
    const bf16* gB = Bt + (size_t)(bn * 256 + w * 8 + lrow) * K + lslot * 8;
    bf16* lA0 = &lds[0][0][0] + w * 512;
    bf16* lB0 = &lds[0][1][0] + w * 512;
    bf16* lA1 = &lds[1][0][0] + w * 512;
    bf16* lB1 = &lds[1][1][0] + w * 512;

    f32x4 acc[8][4];
#pragma unroll
    for (int i = 0; i < 8; ++i)
#pragma unroll
        for (int j = 0; j < 4; ++j) acc[i][j] = {0.f, 0.f, 0.f, 0.f};

// stage K-tile t (8 global_load_lds per wave = the vmcnt unit of account)
#define STAGE(T, LA, LB)                                                  \
    do {                                                                  \
        const bf16* _ga = gA + (size_t)(T) * 64;                          \
        const bf16* _gb = gB + (size_t)(T) * 64;                          \
        _Pragma("unroll") for (int r = 0; r < 4; ++r)                     \
            gload_lds16(_ga + (size_t)r * (64 * K), (LA) + r * 4096);     \
        _Pragma("unroll") for (int r = 0; r < 4; ++r)                     \
            gload_lds16(_gb + (size_t)r * (64 * K), (LB) + r * 4096);     \
    } while (0)

// ds_read a 4-frag A subtile / 4-frag B subtile (swizzled addresses)
#define LDA4(BUF, MH, KS)                                                             \
    _Pragma("unroll") for (int mt = 0; mt < 4; ++mt) {                                \
        int row = wm * 128 + (MH) * 64 + mt * 16 + fr;                                \
        int sl = (((KS) << 2) | fq) ^ sx;                                             \
        af[mt] = *(const bf16x8*)((const char*)&lds[BUF][0][0] + row * 128 + sl * 16);\
    }
#define LDB4(BUF, KS)                                                                 \
    _Pragma("unroll") for (int nt = 0; nt < 4; ++nt) {                                \
        int row = wn * 64 + nt * 16 + fr;                                             \
        int sl = (((KS) << 2) | fq) ^ sx;                                             \
        bq[nt] = *(const bf16x8*)((const char*)&lds[BUF][1][0] + row * 128 + sl * 16);\
    }
#define MFMA16(MH)                                                                    \
    _Pragma("unroll") for (int mt = 0; mt < 4; ++mt)                                  \
    _Pragma("unroll") for (int nt = 0; nt < 4; ++nt)                                  \
        acc[(MH) * 4 + mt][nt] = __builtin_amdgcn_mfma_f32_16x16x32_bf16(             \
            af[mt], bq[nt], acc[(MH) * 4 + mt][nt], 0, 0, 0);

    // prologue: tiles 0 and 1 in flight; wait only tile 0 (8 newest stay in flight)
    STAGE(0, lA0, lB0);
    STAGE(1, lA1, lB1);
    WAITV(8);
    SBAR();

#pragma unroll 2
    for (int t = 0; t < NT; ++t) {
        const int b = t & 1;
        bf16x8 af[4], bq[4];
        // phase 1: (ks=0, mh=0) + B(ks=0)
        LDB4(b, 0); LDA4(b, 0, 0);
        SBAR(); WAITL0();
        __builtin_amdgcn_s_setprio(1); MFMA16(0); __builtin_amdgcn_s_setprio(0);
        SBAR();
        // phase 2: (ks=0, mh=1), reuse B(ks=0)
        LDA4(b, 1, 0);
        SBAR(); WAITL0();
        __builtin_amdgcn_s_setprio(1); MFMA16(1); __builtin_amdgcn_s_setprio(0);
        SBAR();
        // phase 3: (ks=1, mh=0) + B(ks=1)
        LDB4(b, 1); LDA4(b, 0, 1);
        SBAR(); WAITL0();
        __builtin_amdgcn_s_setprio(1); MFMA16(0); __builtin_amdgcn_s_setprio(0);
        SBAR();
        // phase 4: (ks=1, mh=1)
        LDA4(b, 1, 1);
        SBAR(); WAITL0();
        __builtin_amdgcn_s_setprio(1); MFMA16(1); __builtin_amdgcn_s_setprio(0);
        SBAR();
        // boundary: buffer b is dead (every wave executed lgkm(0) before the
        // barrier above -> its reads of b are complete). Prefetch tile t+2 into
        // it; counted wait ensures tile t+1 landed while t+2's 8 loads stay in
        // flight across the barrier.
        if (t + 2 < NT) {
            if (b == 0) { STAGE(t + 2, lA0, lB0); } else { STAGE(t + 2, lA1, lB1); }
            WAITV(8);
            SBAR();
        } else if (t + 1 < NT) {
            WAITV(0);
            SBAR();
        }
    }
#undef STAGE
#undef LDA4
#undef LDB4
#undef MFMA16

    // epilogue: C/D layout (verified m89/m91): col = lane&15, row = (lane>>4)*4 + reg
    float bv[4];
    if (RELU_BIAS) {
#pragma unroll
        for (int nt = 0; nt < 4; ++nt) {
            int col = bn * 256 + wn * 64 + nt * 16 + fr;
            bv[nt] = (col < DMID) ? bias[col] : 0.0f;
        }
    }
#pragma unroll
    for (int mq = 0; mq < 8; ++mq) {
        int row0 = bm * 256 + wm * 128 + mq * 16 + fq * 4;
#pragma unroll
        for (int nt = 0; nt < 4; ++nt) {
            int col = bn * 256 + wn * 64 + nt * 16 + fr;
#pragma unroll
            for (int r = 0; r < 4; ++r) {
                float v = acc[mq][nt][r];
                if (RELU_BIAS) v = fmaxf(v + bv[nt], 0.0f);
                C[(size_t)(row0 + r) * N + col] = (bf16)v;
            }
        }
    }
}

// ---------------- aggregation (CSR gather, barrier-free) ----------------
// XA[i] = isd_i^2 * X[i] + sum_j w_ij * X[j], 1024-wide bf16 in/out
__global__ __launch_bounds__(128) void k_aggX(const bf16* __restrict__ X,
                                              const int* __restrict__ rowptr,
                                              const int* __restrict__ csr_src,
                                              const float* __restrict__ csr_w,
                                              const float* __restrict__ isd,
                                              bf16* __restrict__ XA) {
    int i = blockIdx.x;
    int t = threadIdx.x;      // 128 threads * 8 cols = 1024
    int c0 = t * 8;
    int beg = rowptr[i], end = rowptr[i + 1];  // uniform; (end-beg) % 8 == 0
    float wi = isd[i];
    float w0 = wi * wi;
    float a[8];
    bf16x8 h = *(const bf16x8*)&X[(size_t)i * DIN + c0];
#pragma unroll
    for (int k = 0; k < 8; ++k) a[k] = w0 * (float)h[k];
    for (int e = beg; e < end; e += 8) {
        int j[8];
        float w[8];
        bf16x8 hv[8];
#pragma unroll
        for (int q = 0; q < 8; ++q) { j[q] = csr_src[e + q]; w[q] = csr_w[e + q]; }
#pragma unroll
        for (int q = 0; q < 8; ++q)
            hv[q] = *(const bf16x8*)&X[(size_t)j[q] * DIN + c0];
#pragma unroll
        for (int q = 0; q < 8; ++q)
#pragma unroll
            for (int k = 0; k < 8; ++k) a[k] += w[q] * (float)hv[q][k];
    }
    bf16x8 o;
#pragma unroll
    for (int k = 0; k < 8; ++k) o[k] = (bf16)a[k];
    *(bf16x8*)&XA[(size_t)i * DIN + c0] = o;
}

// layer 2: out[i] = isd_i^2 * H[i] + sum_j w_ij * H[j] + b2, f32 out
__global__ __launch_bounds__(128) void k_agg2(const bf16* __restrict__ H,
                                              const int* __restrict__ rowptr,
                                              const int* __restrict__ csr_src,
                                              const float* __restrict__ csr_w,
                                              const float* __restrict__ isd,
                                              const float* __restrict__ b2,
                                              float* __restrict__ out) {
    int i = blockIdx.x;
    int t = threadIdx.x;      // 128 threads * 8 cols = 1024
    int c0 = t * 8;
    int beg = rowptr[i], end = rowptr[i + 1];
    float wi = isd[i];
    float w0 = wi * wi;
    float a[8];
    bf16x8 h = *(const bf16x8*)&H[(size_t)i * DIN + c0];
#pragma unroll
    for (int k = 0; k < 8; ++k) a[k] = w0 * (float)h[k];
    for (int e = beg; e < end; e += 8) {
        int j[8];
        float w[8];
        bf16x8 hv[8];
#pragma unroll
        for (int q = 0; q < 8; ++q) { j[q] = csr_src[e + q]; w[q] = csr_w[e + q]; }
#pragma unroll
        for (int q = 0; q < 8; ++q)
            hv[q] = *(const bf16x8*)&H[(size_t)j[q] * DIN + c0];
#pragma unroll
        for (int q = 0; q < 8; ++q)
#pragma unroll
            for (int k = 0; k < 8; ++k) a[k] += w[q] * (float)hv[q][k];
    }
    float4 o0, o1;
    o0.x = a[0] + b2[c0 + 0]; o0.y = a[1] + b2[c0 + 1];
    o0.z = a[2] + b2[c0 + 2]; o0.w = a[3] + b2[c0 + 3];
    o1.x = a[4] + b2[c0 + 4]; o1.y = a[5] + b2[c0 + 5];
    o1.z = a[6] + b2[c0 + 6]; o1.w = a[7] + b2[c0 + 7];
    *(float4*)&out[(size_t)i * DIN + c0] = o0;
    *(float4*)&out[(size_t)i * DIN + c0 + 4] = o1;
}

extern "C" void kernel_launch(void* const* d_in, const int* in_sizes, int n_in,
                              void* d_out, int out_size, void* d_ws, size_t ws_size,
                              hipStream_t stream) {
    const float* x = (const float*)d_in[0];
    const int* ei = (const int*)d_in[1];
    const float* W1 = (const float*)d_in[2];
    const float* b1 = (const float*)d_in[3];
    const float* W2 = (const float*)d_in[4];
    const float* b2 = (const float*)d_in[5];
    float* out = (float*)d_out;
    const int* src = ei;
    const int* dst = ei + NE;

    // workspace layout (bytes), total ~122 MB
    char* ws = (char*)d_ws;
    int* cnt      = (int*)(ws + 0);          //  64 KB
    int* cursor   = (int*)(ws + 65536);      //  64 KB
    float* isd    = (float*)(ws + 131072);   //  64 KB
    int* rowptr   = (int*)(ws + 196608);     // 128 KB (NN+1 ints)
    int* csr_src  = (int*)(ws + 327680);     //   2 MB (padded <= 245760 entries)
    float* csr_w  = (float*)(ws + 2424832);  //   2 MB
    bf16* Xb      = (bf16*)(ws + 4521984);   // 33.55 MB (16384x1024)
    bf16* XA      = (bf16*)(ws + 38076416);  // 33.55 MB — reused as H2b
    bf16* W1b     = (bf16*)(ws + 71630848);  //  3.15 MB (1536x1024, transposed)
    bf16* W2b     = (bf16*)(ws + 74776576);  //  3.15 MB (1024x1536, transposed)
    bf16* Y1b     = (bf16*)(ws + 77922304);  // 50.33 MB (16384x1536)
    bf16* H2b     = XA;                      // XA dead after GEMM1

    // CSR + normalization
    k_zero_cnt<<<NN / 256, 256, 0, stream>>>(cnt);
    k_count<<<NE / 256, 256, 0, stream>>>(dst, cnt);
    k_scan<<<1, 1024, 0, stream>>>(cnt, rowptr, cursor, isd);
    k_fill<<<NE / 256, 256, 0, stream>>>(src, dst, cursor, isd, csr_src, csr_w);
    k_pad<<<NN / 256, 256, 0, stream>>>(cnt, rowptr, csr_src, csr_w);

    // bf16 conversions
    k_cvt_x<<<NN * DIN / 4 / 256, 256, 0, stream>>>((const float4*)x, (bf16x4*)Xb);
    k_cvt_w1<<<DMIDP, 256, 0, stream>>>(W1, W1b);
    k_cvt_w2<<<DIN, 256, 0, stream>>>(W2, W2b);

    // layer 1: XA = A_hat @ X ; Y1 = relu(XA @ W1 + b1)   [agg commutes with linear]
    k_aggX<<<NN, 128, 0, stream>>>(Xb, rowptr, csr_src, csr_w, isd, XA);
    dim3 g1(NN / 256, DMIDP / 256);
    gemm256<DIN, DMIDP, true><<<g1, 512, 0, stream>>>(XA, W1b, Y1b, b1);

    // layer 2: H2 = Y1 @ W2 ; out = A_hat @ H2 + b2
    dim3 g2(NN / 256, DIN / 256);
    gemm256<DMIDP, DIN, false><<<g2, 512, 0, stream>>>(Y1b, W2b, H2b, nullptr);
    k_agg2<<<NN, 128, 0, stream>>>(H2b, rowptr, csr_src, csr_w, isd, b2, out);
}

// Round 3
// 378.066 us; speedup vs baseline: 1.1456x; 1.0531x over previous
//
#include <hip/hip_runtime.h>
#include <cstdint>
#include <cstddef>

// Problem constants (fixed by the reference)
#define NN 16384      // nodes
#define DIN 1024      // hid_size
#define DMID 1500     // hidden_size (logical)
#define DMIDP 1536    // padded to multiple of 256
#define NE 131072     // edges

typedef __bf16 bf16;
typedef __bf16 bf16x4 __attribute__((ext_vector_type(4)));
typedef __bf16 bf16x8 __attribute__((ext_vector_type(8)));
typedef float f32x4 __attribute__((ext_vector_type(4)));

#define GLOBAL_AS __attribute__((address_space(1)))
#define LDS_AS __attribute__((address_space(3)))

__device__ __forceinline__ void gload_lds16(const bf16* g, bf16* l) {
    // async 16B/lane global->LDS; LDS dest is wave-uniform base + lane*16
    __builtin_amdgcn_global_load_lds((GLOBAL_AS const unsigned int*)(g),
                                     (LDS_AS unsigned int*)(l), 16, 0, 0);
}

#define SBAR() asm volatile("s_barrier" ::: "memory")
#define WAITV_(N) asm volatile("s_waitcnt vmcnt(" #N ")" ::: "memory")
#define WAITV(N) WAITV_(N)
#define WAITL0() asm volatile("s_waitcnt lgkmcnt(0)" ::: "memory")

// ---------------- CSR build + normalization ----------------
__global__ void k_zero_cnt(int* cnt) {
    cnt[blockIdx.x * 256 + threadIdx.x] = 0;
}

__global__ void k_count(const int* __restrict__ dst, int* cnt) {
    int e = blockIdx.x * 256 + threadIdx.x;
    atomicAdd(&cnt[dst[e]], 1);
}

// single block, 1024 threads, 16 nodes each.
// rowptr = exclusive scan of PADDED counts (pad to multiple of 8); cursor = start; isd.
__global__ __launch_bounds__(1024) void k_scan(const int* __restrict__ cnt,
                                               int* __restrict__ rowptr,
                                               int* __restrict__ cursor,
                                               float* __restrict__ isd) {
    __shared__ int sums[1024];
    int t = threadIdx.x;
    int base = t * 16;
    int v[16], p[16];
    int s = 0;
#pragma unroll
    for (int k = 0; k < 16; ++k) {
        v[k] = cnt[base + k];
        p[k] = (v[k] + 7) & ~7;  // padded row length (multiple of 8)
        s += p[k];
    }
    sums[t] = s;
    __syncthreads();
    for (int off = 1; off < 1024; off <<= 1) {
        int y = (t >= off) ? sums[t - off] : 0;
        __syncthreads();
        sums[t] += y;
        __syncthreads();
    }
    int run = sums[t] - s;  // exclusive prefix
#pragma unroll
    for (int k = 0; k < 16; ++k) {
        rowptr[base + k] = run;
        cursor[base + k] = run;
        isd[base + k] = rsqrtf((float)(v[k] + 1));  // +1 self-loop
        run += p[k];
    }
    if (t == 1023) rowptr[NN] = run;
}

__global__ void k_fill(const int* __restrict__ src, const int* __restrict__ dst,
                       int* cursor, const float* __restrict__ isd,
                       int* __restrict__ csr_src, float* __restrict__ csr_w) {
    int e = blockIdx.x * 256 + threadIdx.x;
    int s = src[e], d = dst[e];
    int pos = atomicAdd(&cursor[d], 1);
    csr_src[pos] = s;
    csr_w[pos] = isd[s] * isd[d];
}

// fill pad slots: src = self (L1-hot row), w = 0 (contributes nothing)
__global__ void k_pad(const int* __restrict__ cnt, const int* __restrict__ rowptr,
                      int* __restrict__ csr_src, float* __restrict__ csr_w) {
    int i = blockIdx.x * 256 + threadIdx.x;
    int c = cnt[i];
    int p = (c + 7) & ~7;
    int base = rowptr[i];
    for (int q = c; q < p; ++q) {
        csr_src[base + q] = i;
        csr_w[base + q] = 0.0f;
    }
}

// ---------------- conversions ----------------
__global__ void k_cvt_x(const float4* __restrict__ x, bf16x4* __restrict__ xb) {
    int i = blockIdx.x * 256 + threadIdx.x;  // NN*DIN/4 total
    float4 v = x[i];
    bf16x4 o;
    o[0] = (bf16)v.x; o[1] = (bf16)v.y; o[2] = (bf16)v.z; o[3] = (bf16)v.w;
    xb[i] = o;
}

// W1 [1024][1500] f32 row-major -> W1b [1536][1024] bf16 (transposed, n-pad zero)
__global__ void k_cvt_w1(const float* __restrict__ W1, bf16* __restrict__ W1b) {
    int n = blockIdx.x;  // 0..1535
    for (int k = threadIdx.x; k < DIN; k += 256)
        W1b[n * DIN + k] = (n < DMID) ? (bf16)W1[(size_t)k * DMID + n] : (bf16)0.0f;
}

// W2 [1500][1024] f32 row-major -> W2b [1024][1536] bf16 (transposed, k-pad zero)
__global__ void k_cvt_w2(const float* __restrict__ W2, bf16* __restrict__ W2b) {
    int n = blockIdx.x;  // 0..1023
    for (int k = threadIdx.x; k < DMIDP; k += 256)
        W2b[n * DMIDP + k] = (k < DMID) ? (bf16)W2[(size_t)k * DIN + n] : (bf16)0.0f;
}

// ---------------- GEMM: C[M,N] = A[M,K] @ Bt[N,K]^T, bf16 in / bf16 out ----------------
// 256x256 tile, BK=64, 8 waves (2M x 4N), per-wave 128x64 output.
// T2: XOR bank-swizzle (conflicts measured 0 in R1/R2).
// R3 restructure (post-mortem R2): the per-phase {reads -> barrier -> lgkm(0) ->
// MFMA -> barrier} lockstep strictly ALTERNATED the LDS pipe (768 cy/phase) and
// the matrix pipe (512 cy/phase) -> 27% MfmaUtil, the 2-phase anchor (m248v2).
// Now: fragment-level software pipeline — each region issues NEXT phase's
// ds_reads into the alternate frag set, then MFMAs the current set; compiler
// emits counted lgkm waits, so MFMA(k) covers the drain of reads(k+1).
// ONE barrier per K-tile at the boundary:
//   lgkm(0)  : own reads of buf b drained (WAR before restaging b)
//   vmcnt(0) : tile t+1's 8 gloads landed (issued a full tile ago -> cold)
//   s_barrier: makes both cross-wave; then STAGE(t+2 -> b) + next ph1 reads.
// Frag lifetime audit: A alternates per phase (A(0,0) dead after MFMA ph1,
// rewritten one region later). B0 used ph1-2, rewritten at boundary; B1 used
// ph3-4, rewritten in R2 of the NEXT tile — both ≥1 full region after last use.
template <int K, int N, bool RELU_BIAS>
__global__ __launch_bounds__(512, 2) void gemm256(const bf16* __restrict__ A,
                                                  const bf16* __restrict__ Bt,
                                                  bf16* __restrict__ C,
                                                  const float* __restrict__ bias) {
    constexpr int NT = K / 64;
    __shared__ __align__(16) bf16 lds[2][2][256 * 64];  // [buf][A/B] = 128 KB
    const int tid = threadIdx.x;
    const int w = tid >> 6;
    const int lane = tid & 63;
    const int bm = blockIdx.x, bn = blockIdx.y;
    const int fr = lane & 15, fq = lane >> 4;
    const int wm = w >> 2;   // 0..1 : M half (128 rows)
    const int wn = w & 3;    // 0..3 : N quarter (64 cols)
    const int sx = fr & 7;   // read-side swizzle mask

    // staging: wave w, round r covers tile rows r*64 + w*8 .. +7 (1 KB per gload).
    // lane l -> row_local = l>>3; fetch global slot (l&7)^(l>>3) so the linear
    // LDS write lands pre-swizzled (both-sides involution, rule #21).
    const int lrow = lane >> 3;
    const int lslot = (lane & 7) ^ lrow;
    const bf16* gA = A + (size_t)(bm * 256 + w * 8 + lrow) * K + lslot * 8;
    const bf16* gB = Bt + (size_t)(bn * 256 + w * 8 + lrow) * K + lslot * 8;

    f32x4 acc[8][4];
#pragma unroll
    for (int i = 0; i < 8; ++i)
#pragma unroll
        for (int j = 0; j < 4; ++j) acc[i][j] = {0.f, 0.f, 0.f, 0.f};

#define STAGE(T, BUF)                                                          \
    do {                                                                       \
        const bf16* _ga = gA + (size_t)(T) * 64;                               \
        const bf16* _gb = gB + (size_t)(T) * 64;                               \
        bf16* _la = &lds[BUF][0][0] + w * 512;                                 \
        bf16* _lb = &lds[BUF][1][0] + w * 512;                                 \
        _Pragma("unroll") for (int r = 0; r < 4; ++r)                          \
            gload_lds16(_ga + (size_t)r * (64 * K), _la + r * 4096);           \
        _Pragma("unroll") for (int r = 0; r < 4; ++r)                          \
            gload_lds16(_gb + (size_t)r * (64 * K), _lb + r * 4096);           \
    } while (0)

// ds_read 4 A-frags (dest set DST) / 4 B-frags, swizzled addresses
#define LDA4(DST, BUF, MH, KS)                                                 \
    _Pragma("unroll") for (int mt = 0; mt < 4; ++mt) {                         \
        int row = wm * 128 + (MH) * 64 + mt * 16 + fr;                         \
        int sl = (((KS) << 2) | fq) ^ sx;                                      \
        DST[mt] = *(const bf16x8*)((const char*)&lds[BUF][0][0] +              \
                                   row * 128 + sl * 16);                       \
    }
#define LDB4(DST, BUF, KS)                                                     \
    _Pragma("unroll") for (int nt = 0; nt < 4; ++nt) {                         \
        int row = wn * 64 + nt * 16 + fr;                                      \
        int sl = (((KS) << 2) | fq) ^ sx;                                      \
        DST[nt] = *(const bf16x8*)((const char*)&lds[BUF][1][0] +              \
                                   row * 128 + sl * 16);                       \
    }
#define MFMA16(MH, AF, BF)                                                     \
    __builtin_amdgcn_s_setprio(1);                                             \
    _Pragma("unroll") for (int mt = 0; mt < 4; ++mt)                           \
    _Pragma("unroll") for (int nt = 0; nt < 4; ++nt)                           \
        acc[(MH) * 4 + mt][nt] = __builtin_amdgcn_mfma_f32_16x16x32_bf16(      \
            AF[mt], BF[nt], acc[(MH) * 4 + mt][nt], 0, 0, 0);                  \
    __builtin_amdgcn_s_setprio(0);

    bf16x8 a0[4], a1[4], b0[4], b1[4];

    // prologue: tiles 0,1 in flight; wait tile 0 (tile 1's 8 stay outstanding)
    STAGE(0, 0);
    STAGE(1, 1);
    WAITV(8);
    SBAR();
    LDA4(a0, 0, 0, 0);   // tile0 ph1 A-frags
    LDB4(b0, 0, 0);      // tile0 B(ks=0)

    for (int t = 0; t < NT; ++t) {
        const int b = t & 1;
        // R1: prefetch ph2 frags, MFMA ph1 (mh0, ks0)
        LDA4(a1, b, 1, 0);
        MFMA16(0, a0, b0);
        // R2: prefetch ph3 frags (A mh0 ks1 + B ks1), MFMA ph2 (mh1, ks0)
        LDA4(a0, b, 0, 1);
        LDB4(b1, b, 1);
        MFMA16(1, a1, b0);
        // R3: prefetch ph4 frags, MFMA ph3 (mh0, ks1)
        LDA4(a1, b, 1, 1);
        MFMA16(0, a0, b1);
        // R4: tile boundary. Drain own b-reads (WAR) + t+1's gloads (RAW, cold:
        // issued a full tile ago), one barrier, restage b, read next ph1 frags.
        if (t + 1 < NT) {
            WAITL0();
            WAITV(0);
            SBAR();
            if (t + 2 < NT) STAGE(t + 2, b);
            LDA4(a0, b ^ 1, 0, 0);
            LDB4(b0, b ^ 1, 0);
        }
        // MFMA ph4 (mh1, ks1) — register-only, free to overlap the above
        MFMA16(1, a1, b1);
    }
#undef STAGE
#undef LDA4
#undef LDB4
#undef MFMA16

    // epilogue: C/D layout (verified m89/m91): col = lane&15, row = (lane>>4)*4 + reg
    float bv[4];
    if (RELU_BIAS) {
#pragma unroll
        for (int nt = 0; nt < 4; ++nt) {
            int col = bn * 256 + wn * 64 + nt * 16 + fr;
            bv[nt] = (col < DMID) ? bias[col] : 0.0f;
        }
    }
#pragma unroll
    for (int mq = 0; mq < 8; ++mq) {
        int row0 = bm * 256 + wm * 128 + mq * 16 + fq * 4;
#pragma unroll
        for (int nt = 0; nt < 4; ++nt) {
            int col = bn * 256 + wn * 64 + nt * 16 + fr;
#pragma unroll
            for (int r = 0; r < 4; ++r) {
                float v = acc[mq][nt][r];
                if (RELU_BIAS) v = fmaxf(v + bv[nt], 0.0f);
                C[(size_t)(row0 + r) * N + col] = (bf16)v;
            }
        }
    }
}

// ---------------- aggregation (CSR gather, barrier-free) ----------------
// XA[i] = isd_i^2 * X[i] + sum_j w_ij * X[j], 1024-wide bf16 in/out
__global__ __launch_bounds__(128) void k_aggX(const bf16* __restrict__ X,
                                              const int* __restrict__ rowptr,
                                              const int* __restrict__ csr_src,
                                              const float* __restrict__ csr_w,
                                              const float* __restrict__ isd,
                                              bf16* __restrict__ XA) {
    int i = blockIdx.x;
    int t = threadIdx.x;      // 128 threads * 8 cols = 1024
    int c0 = t * 8;
    int beg = rowptr[i], end = rowptr[i + 1];  // uniform; (end-beg) % 8 == 0
    float wi = isd[i];
    float w0 = wi * wi;
    float a[8];
    bf16x8 h = *(const bf16x8*)&X[(size_t)i * DIN + c0];
#pragma unroll
    for (int k = 0; k < 8; ++k) a[k] = w0 * (float)h[k];
    for (int e = beg; e < end; e += 8) {
        int j[8];
        float w[8];
        bf16x8 hv[8];
#pragma unroll
        for (int q = 0; q < 8; ++q) { j[q] = csr_src[e + q]; w[q] = csr_w[e + q]; }
#pragma unroll
        for (int q = 0; q < 8; ++q)
            hv[q] = *(const bf16x8*)&X[(size_t)j[q] * DIN + c0];
#pragma unroll
        for (int q = 0; q < 8; ++q)
#pragma unroll
            for (int k = 0; k < 8; ++k) a[k] += w[q] * (float)hv[q][k];
    }
    bf16x8 o;
#pragma unroll
    for (int k = 0; k < 8; ++k) o[k] = (bf16)a[k];
    *(bf16x8*)&XA[(size_t)i * DIN + c0] = o;
}

// layer 2: out[i] = isd_i^2 * H[i] + sum_j w_ij * H[j] + b2, f32 out
__global__ __launch_bounds__(128) void k_agg2(const bf16* __restrict__ H,
                                              const int* __restrict__ rowptr,
                                              const int* __restrict__ csr_src,
                                              const float* __restrict__ csr_w,
                                              const float* __restrict__ isd,
                                              const float* __restrict__ b2,
                                              float* __restrict__ out) {
    int i = blockIdx.x;
    int t = threadIdx.x;      // 128 threads * 8 cols = 1024
    int c0 = t * 8;
    int beg = rowptr[i], end = rowptr[i + 1];
    float wi = isd[i];
    float w0 = wi * wi;
    float a[8];
    bf16x8 h = *(const bf16x8*)&H[(size_t)i * DIN + c0];
#pragma unroll
    for (int k = 0; k < 8; ++k) a[k] = w0 * (float)h[k];
    for (int e = beg; e < end; e += 8) {
        int j[8];
        float w[8];
        bf16x8 hv[8];
#pragma unroll
        for (int q = 0; q < 8; ++q) { j[q] = csr_src[e + q]; w[q] = csr_w[e + q]; }
#pragma unroll
        for (int q = 0; q < 8; ++q)
            hv[q] = *(const bf16x8*)&H[(size_t)j[q] * DIN + c0];
#pragma unroll
        for (int q = 0; q < 8; ++q)
#pragma unroll
            for (int k = 0; k < 8; ++k) a[k] += w[q] * (float)hv[q][k];
    }
    float4 o0, o1;
    o0.x = a[0] + b2[c0 + 0]; o0.y = a[1] + b2[c0 + 1];
    o0.z = a[2] + b2[c0 + 2]; o0.w = a[3] + b2[c0 + 3];
    o1.x = a[4] + b2[c0 + 4]; o1.y = a[5] + b2[c0 + 5];
    o1.z = a[6] + b2[c0 + 6]; o1.w = a[7] + b2[c0 + 7];
    *(float4*)&out[(size_t)i * DIN + c0] = o0;
    *(float4*)&out[(size_t)i * DIN + c0 + 4] = o1;
}

extern "C" void kernel_launch(void* const* d_in, const int* in_sizes, int n_in,
                              void* d_out, int out_size, void* d_ws, size_t ws_size,
                              hipStream_t stream) {
    const float* x = (const float*)d_in[0];
    const int* ei = (const int*)d_in[1];
    const float* W1 = (const float*)d_in[2];
    const float* b1 = (const float*)d_in[3];
    const float* W2 = (const float*)d_in[4];
    const float* b2 = (const float*)d_in[5];
    float* out = (float*)d_out;
    const int* src = ei;
    const int* dst = ei + NE;

    // workspace layout (bytes), total ~122 MB
    char* ws = (char*)d_ws;
    int* cnt      = (int*)(ws + 0);          //  64 KB
    int* cursor   = (int*)(ws + 65536);      //  64 KB
    float* isd    = (float*)(ws + 131072);   //  64 KB
    int* rowptr   = (int*)(ws + 196608);     // 128 KB (NN+1 ints)
    int* csr_src  = (int*)(ws + 327680);     //   2 MB (padded <= 245760 entries)
    float* csr_w  = (float*)(ws + 2424832);  //   2 MB
    bf16* Xb      = (bf16*)(ws + 4521984);   // 33.55 MB (16384x1024)
    bf16* XA      = (bf16*)(ws + 38076416);  // 33.55 MB — reused as H2b
    bf16* W1b     = (bf16*)(ws + 71630848);  //  3.15 MB (1536x1024, transposed)
    bf16* W2b     = (bf16*)(ws + 74776576);  //  3.15 MB (1024x1536, transposed)
    bf16* Y1b     = (bf16*)(ws + 77922304);  // 50.33 MB (16384x1536)
    bf16* H2b     = XA;                      // XA dead after GEMM1

    // CSR + normalization
    k_zero_cnt<<<NN / 256, 256, 0, stream>>>(cnt);
    k_count<<<NE / 256, 256, 0, stream>>>(dst, cnt);
    k_scan<<<1, 1024, 0, stream>>>(cnt, rowptr, cursor, isd);
    k_fill<<<NE / 256, 256, 0, stream>>>(src, dst, cursor, isd, csr_src, csr_w);
    k_pad<<<NN / 256, 256, 0, stream>>>(cnt, rowptr, csr_src, csr_w);

    // bf16 conversions
    k_cvt_x<<<NN * DIN / 4 / 256, 256, 0, stream>>>((const float4*)x, (bf16x4*)Xb);
    k_cvt_w1<<<DMIDP, 256, 0, stream>>>(W1, W1b);
    k_cvt_w2<<<DIN, 256, 0, stream>>>(W2, W2b);

    // layer 1: XA = A_hat @ X ; Y1 = relu(XA @ W1 + b1)   [agg commutes with linear]
    k_aggX<<<NN, 128, 0, stream>>>(Xb, rowptr, csr_src, csr_w, isd, XA);
    dim3 g1(NN / 256, DMIDP / 256);
    gemm256<DIN, DMIDP, true><<<g1, 512, 0, stream>>>(XA, W1b, Y1b, b1);

    // layer 2: H2 = Y1 @ W2 ; out = A_hat @ H2 + b2
    dim3 g2(NN / 256, DIN / 256);
    gemm256<DMIDP, DIN, false><<<g2, 512, 0, stream>>>(Y1b, W2b, H2b, nullptr);
    k_agg2<<<NN, 128, 0, stream>>>(H2b, rowptr, csr_src, csr_w, isd, b2, out);
}